// Round 1
// baseline (1108.478 us; speedup 1.0000x reference)
//
#include <hip/hip_runtime.h>
#include <math.h>

namespace {
constexpr int B_ = 128;
constexpr int S_ = 64;
constexpr int H_ = 1000;
constexpr int A_ = 1000;
constexpr int M_ = 500;   // maxout dim
constexpr int V_ = 30000;
constexpr int E_ = 620;
constexpr int CAT = H_ + E_ + 2 * H_;   // 3620 : [hidden | emb_x | ctx]
constexpr int GRUK = E_ + 2 * H_;       // 2620 : [emb_x | ctx]

constexpr int TK = 16;

enum { EP_BIAS = 0, EP_ACCBIAS = 1, EP_ACC_MAXPAIR = 2 };

__device__ __forceinline__ float sigmoidf_(float x) {
  return 1.0f / (1.0f + __expf(-x));
}
}  // namespace

// ---------------------------------------------------------------------------
// Generic 64x64-tile fp32 GEMM: C[M,N] = A[M,K] @ B[N,K]^T (+ epilogue)
// A row-major lda, B row-major ldb (used transposed). 256 threads, 4x4/thread.
// ---------------------------------------------------------------------------
template <int EPI>
__global__ __launch_bounds__(256) void gemm_tn(
    const float* __restrict__ Amat, int lda,
    const float* __restrict__ Bmat, int ldb,
    float* __restrict__ Cout, int ldc,
    int M, int N, int K,
    const float* __restrict__ bias,
    const float* __restrict__ moin)  // EP_ACC_MAXPAIR: previously accumulated mo_in
{
  __shared__ __align__(16) float As[TK][64];
  __shared__ __align__(16) float Bs[TK][64];

  const int t = threadIdx.x;
  const int m0 = blockIdx.x * 64;
  const int n0 = blockIdx.y * 64;
  const int tr = t >> 4;       // 0..15
  const int tc = t & 15;       // 0..15
  const int lrow = t >> 2;     // 0..63
  const int lk = (t & 3) * 4;  // 0,4,8,12

  float acc[4][4] = {};

  for (int k0 = 0; k0 < K; k0 += TK) {
    const int gk = k0 + lk;
    // global loads into regs
    float4 av = make_float4(0.f, 0.f, 0.f, 0.f);
    {
      const int gr = m0 + lrow;
      if (gr < M) {
        if (gk + 3 < K) {
          av = *(const float4*)(Amat + (size_t)gr * lda + gk);
        } else {
          float tmp[4] = {0.f, 0.f, 0.f, 0.f};
          for (int i = 0; i < 4; ++i)
            if (gk + i < K) tmp[i] = Amat[(size_t)gr * lda + gk + i];
          av = make_float4(tmp[0], tmp[1], tmp[2], tmp[3]);
        }
      }
    }
    float4 bv = make_float4(0.f, 0.f, 0.f, 0.f);
    {
      const int gr = n0 + lrow;
      if (gr < N) {
        if (gk + 3 < K) {
          bv = *(const float4*)(Bmat + (size_t)gr * ldb + gk);
        } else {
          float tmp[4] = {0.f, 0.f, 0.f, 0.f};
          for (int i = 0; i < 4; ++i)
            if (gk + i < K) tmp[i] = Bmat[(size_t)gr * ldb + gk + i];
          bv = make_float4(tmp[0], tmp[1], tmp[2], tmp[3]);
        }
      }
    }
    __syncthreads();  // previous tile's compute done
    As[lk + 0][lrow] = av.x; As[lk + 1][lrow] = av.y;
    As[lk + 2][lrow] = av.z; As[lk + 3][lrow] = av.w;
    Bs[lk + 0][lrow] = bv.x; Bs[lk + 1][lrow] = bv.y;
    Bs[lk + 2][lrow] = bv.z; Bs[lk + 3][lrow] = bv.w;
    __syncthreads();

#pragma unroll
    for (int kk = 0; kk < TK; ++kk) {
      const float4 a4 = *(const float4*)&As[kk][tr * 4];
      const float4 b4 = *(const float4*)&Bs[kk][tc * 4];
      const float aa[4] = {a4.x, a4.y, a4.z, a4.w};
      const float bb[4] = {b4.x, b4.y, b4.z, b4.w};
#pragma unroll
      for (int i = 0; i < 4; ++i)
#pragma unroll
        for (int j = 0; j < 4; ++j)
          acc[i][j] = fmaf(aa[i], bb[j], acc[i][j]);
    }
  }

  // epilogue
  if constexpr (EPI == EP_BIAS) {
#pragma unroll
    for (int i = 0; i < 4; ++i) {
      const int r = m0 + tr * 4 + i;
      if (r >= M) continue;
#pragma unroll
      for (int j = 0; j < 4; ++j) {
        const int c = n0 + tc * 4 + j;
        if (c < N) Cout[(size_t)r * ldc + c] = acc[i][j] + bias[c];
      }
    }
  } else if constexpr (EPI == EP_ACCBIAS) {
#pragma unroll
    for (int i = 0; i < 4; ++i) {
      const int r = m0 + tr * 4 + i;
      if (r >= M) continue;
#pragma unroll
      for (int j = 0; j < 4; ++j) {
        const int c = n0 + tc * 4 + j;
        if (c < N) {
          const size_t idx = (size_t)r * ldc + c;
          Cout[idx] = Cout[idx] + acc[i][j] + bias[c];
        }
      }
    }
  } else {  // EP_ACC_MAXPAIR: v = moin + acc + bias; mo[r][c/2] = max of pairs
#pragma unroll
    for (int i = 0; i < 4; ++i) {
      const int r = m0 + tr * 4 + i;
      if (r >= M) continue;
      const int c0 = n0 + tc * 4;
      if (c0 + 3 < N) {  // N=1000, pairs aligned: either all 4 valid or none
        const float v0 = moin[(size_t)r * N + c0 + 0] + acc[i][0] + bias[c0 + 0];
        const float v1 = moin[(size_t)r * N + c0 + 1] + acc[i][1] + bias[c0 + 1];
        const float v2 = moin[(size_t)r * N + c0 + 2] + acc[i][2] + bias[c0 + 2];
        const float v3 = moin[(size_t)r * N + c0 + 3] + acc[i][3] + bias[c0 + 3];
        Cout[(size_t)r * ldc + (c0 >> 1) + 0] = fmaxf(v0, v1);
        Cout[(size_t)r * ldc + (c0 >> 1) + 1] = fmaxf(v2, v3);
      }
    }
  }
}

// ---------------------------------------------------------------------------
// Dominant kernel: o_proj GEMM (8192x1000, K=2000) with fused
// energy[r] += sum_a tanh(o + b_op[a] + hp[b,a]) * v_e[a]
// 128x128 block tile, 8x8 per thread, atomicAdd partial energies.
// ---------------------------------------------------------------------------
__global__ __launch_bounds__(256) void gemm128_energy(
    const float* __restrict__ outputs,  // (8192, 2000)
    const float* __restrict__ Wop,      // (1000, 2000)
    const float* __restrict__ b_op, const float* __restrict__ hp,
    const float* __restrict__ ve, float* __restrict__ energy)
{
  constexpr int K = 2 * H_;   // 2000
  constexpr int N = A_;       // 1000
  __shared__ __align__(16) float As[TK][128];
  __shared__ __align__(16) float Bs[TK][128];
  __shared__ float red[128][17];

  const int t = threadIdx.x;
  const int m0 = blockIdx.x * 128;
  const int n0 = blockIdx.y * 128;
  const int tr = t >> 4;   // 0..15
  const int tc = t & 15;   // 0..15
  const int lrow = t >> 1;        // 0..127
  const int lk = (t & 1) * 8;     // 0 or 8

  float acc[8][8] = {};

  for (int k0 = 0; k0 < K; k0 += TK) {
    // loads (K=2000 divisible by 16: no K guards)
    const float* Ap = outputs + (size_t)(m0 + lrow) * K + k0 + lk;
    const float4 a0 = *(const float4*)Ap;
    const float4 a1 = *(const float4*)(Ap + 4);
    float4 b0 = make_float4(0.f, 0.f, 0.f, 0.f);
    float4 b1 = make_float4(0.f, 0.f, 0.f, 0.f);
    const int brow = n0 + lrow;
    if (brow < N) {
      const float* Bp = Wop + (size_t)brow * K + k0 + lk;
      b0 = *(const float4*)Bp;
      b1 = *(const float4*)(Bp + 4);
    }
    __syncthreads();
    As[lk + 0][lrow] = a0.x; As[lk + 1][lrow] = a0.y;
    As[lk + 2][lrow] = a0.z; As[lk + 3][lrow] = a0.w;
    As[lk + 4][lrow] = a1.x; As[lk + 5][lrow] = a1.y;
    As[lk + 6][lrow] = a1.z; As[lk + 7][lrow] = a1.w;
    Bs[lk + 0][lrow] = b0.x; Bs[lk + 1][lrow] = b0.y;
    Bs[lk + 2][lrow] = b0.z; Bs[lk + 3][lrow] = b0.w;
    Bs[lk + 4][lrow] = b1.x; Bs[lk + 5][lrow] = b1.y;
    Bs[lk + 6][lrow] = b1.z; Bs[lk + 7][lrow] = b1.w;
    __syncthreads();

#pragma unroll
    for (int kk = 0; kk < TK; ++kk) {
      // split micro-tile {tr*4, 64+tr*4} x {tc*4, 64+tc*4}: 2-way LDS conflicts only
      const float4 x0 = *(const float4*)&As[kk][tr * 4];
      const float4 x1 = *(const float4*)&As[kk][64 + tr * 4];
      const float4 y0 = *(const float4*)&Bs[kk][tc * 4];
      const float4 y1 = *(const float4*)&Bs[kk][64 + tc * 4];
      const float aa[8] = {x0.x, x0.y, x0.z, x0.w, x1.x, x1.y, x1.z, x1.w};
      const float bb[8] = {y0.x, y0.y, y0.z, y0.w, y1.x, y1.y, y1.z, y1.w};
#pragma unroll
      for (int i = 0; i < 8; ++i)
#pragma unroll
        for (int j = 0; j < 8; ++j)
          acc[i][j] = fmaf(aa[i], bb[j], acc[i][j]);
    }
  }

  // fused epilogue: tanh(o + b_op + hp)*v_e, reduce over this block's 128 cols
#pragma unroll
  for (int i = 0; i < 8; ++i) {
    const int ri = (i < 4) ? (tr * 4 + i) : (64 + tr * 4 + (i - 4));
    const int r = m0 + ri;
    const int b = r >> 6;  // row = b*64 + s
    float s = 0.f;
#pragma unroll
    for (int j = 0; j < 8; ++j) {
      const int cj = (j < 4) ? (tc * 4 + j) : (64 + tc * 4 + (j - 4));
      const int c = n0 + cj;
      if (c < N) {
        const float v = acc[i][j] + b_op[c] + hp[(size_t)b * A_ + c];
        s += tanhf(v) * ve[c];
      }
    }
    red[ri][tc] = s;
  }
  __syncthreads();
  if (t < 128) {
    float s = 0.f;
#pragma unroll
    for (int j = 0; j < 16; ++j) s += red[t][j];
    atomicAdd(&energy[m0 + t], s);
  }
}

// ---------------------------------------------------------------------------
// Per-b: softmax over S, ctx = attn @ outputs, build cat3 = [hidden|emb_x|ctx]
// ---------------------------------------------------------------------------
__global__ __launch_bounds__(256) void softmax_ctx_cat(
    const float* __restrict__ energy, const float* __restrict__ outputs,
    const float* __restrict__ hidden, const float* __restrict__ emb,
    const int* __restrict__ x, float* __restrict__ cat3)
{
  const int b = blockIdx.x;
  const int t = threadIdx.x;
  __shared__ float attn[S_];
  __shared__ float sinv;

  if (t == 0) {
    float mx = -1e30f;
    for (int s = 0; s < S_; ++s) mx = fmaxf(mx, energy[b * S_ + s]);
    float sum = 0.f;
    for (int s = 0; s < S_; ++s) {
      const float e = __expf(energy[b * S_ + s] - mx);
      attn[s] = e;
      sum += e;
    }
    sinv = 1.f / sum;
  }
  __syncthreads();
  const float inv = sinv;

  float* catb = cat3 + (size_t)b * CAT;
  // ctx (vectorized float4 over k)
  const float4* out4 = (const float4*)(outputs + (size_t)b * S_ * 2 * H_);
  float4* ctx4 = (float4*)(catb + H_ + E_);
  for (int kk = t; kk < (2 * H_) / 4; kk += 256) {
    float4 a = make_float4(0.f, 0.f, 0.f, 0.f);
    for (int s = 0; s < S_; ++s) {
      const float w = attn[s];
      const float4 o = out4[(size_t)s * (2 * H_ / 4) + kk];
      a.x = fmaf(w, o.x, a.x); a.y = fmaf(w, o.y, a.y);
      a.z = fmaf(w, o.z, a.z); a.w = fmaf(w, o.w, a.w);
    }
    a.x *= inv; a.y *= inv; a.z *= inv; a.w *= inv;
    ctx4[kk] = a;
  }
  // hidden copy
  const float4* hid4 = (const float4*)(hidden + (size_t)b * H_);
  float4* dsth = (float4*)catb;
  for (int kk = t; kk < H_ / 4; kk += 256) dsth[kk] = hid4[kk];
  // emb gather
  const int xi = x[b];
  const float4* emb4 = (const float4*)(emb + (size_t)xi * E_);
  float4* dste = (float4*)(catb + H_);
  for (int kk = t; kk < E_ / 4; kk += 256) dste[kk] = emb4[kk];
}

// ---------------------------------------------------------------------------
// GRU elementwise combine -> h_new
// ---------------------------------------------------------------------------
__global__ __launch_bounds__(256) void gru_combine(
    const float* __restrict__ gi, const float* __restrict__ gh,
    const float* __restrict__ hidden, float* __restrict__ hout)
{
  const int idx = blockIdx.x * 256 + threadIdx.x;
  if (idx >= B_ * H_) return;
  const int b = idx / H_, h = idx - b * H_;
  const float* gib = gi + (size_t)b * 3 * H_;
  const float* ghb = gh + (size_t)b * 3 * H_;
  const float ir = gib[h], iz = gib[H_ + h], in = gib[2 * H_ + h];
  const float hr = ghb[h], hz = ghb[H_ + h], hn = ghb[2 * H_ + h];
  const float r = sigmoidf_(ir + hr);
  const float z = sigmoidf_(iz + hz);
  const float n = tanhf(in + r * hn);
  hout[idx] = (1.f - z) * n + z * hidden[idx];
}

// ---------------------------------------------------------------------------
extern "C" void kernel_launch(void* const* d_in, const int* in_sizes, int n_in,
                              void* d_out, int out_size, void* d_ws, size_t ws_size,
                              hipStream_t stream)
{
  const int*   x       = (const int*)  d_in[0];
  const float* hidden  = (const float*)d_in[1];
  const float* outputs = (const float*)d_in[2];
  const float* emb     = (const float*)d_in[3];
  const float* W_hp    = (const float*)d_in[4];
  const float* b_hp    = (const float*)d_in[5];
  const float* W_op    = (const float*)d_in[6];
  const float* b_op    = (const float*)d_in[7];
  const float* v_e     = (const float*)d_in[8];
  const float* W_ih    = (const float*)d_in[9];
  const float* W_hh    = (const float*)d_in[10];
  const float* b_ih    = (const float*)d_in[11];
  const float* b_hh    = (const float*)d_in[12];
  const float* W_wv    = (const float*)d_in[13];
  const float* b_wv    = (const float*)d_in[14];
  const float* W_lh    = (const float*)d_in[15];
  const float* b_lh    = (const float*)d_in[16];
  const float* W_le    = (const float*)d_in[17];
  const float* b_le    = (const float*)d_in[18];
  const float* W_pred  = (const float*)d_in[19];
  const float* b_pred  = (const float*)d_in[20];

  float* ws = (float*)d_ws;
  float* hp     = ws;                       // 128*1000
  float* energy = hp + B_ * A_;             // 8192
  float* cat3   = energy + B_ * S_;         // 128*3620
  float* gi     = cat3 + (size_t)B_ * CAT;  // 128*3000
  float* gh     = gi + B_ * 3 * H_;         // 128*3000
  float* mo_in  = gh + B_ * 3 * H_;         // 128*1000
  float* mo     = mo_in + B_ * 2 * M_;      // 128*500

  float* pred = (float*)d_out;
  float* hout = pred + (size_t)B_ * V_;

  hipMemsetAsync(energy, 0, B_ * S_ * sizeof(float), stream);

  const dim3 blk(256);

  // h_proj = hidden @ W_hp^T + b_hp
  gemm_tn<EP_BIAS><<<dim3(2, 16), blk, 0, stream>>>(
      hidden, H_, W_hp, H_, hp, A_, B_, A_, H_, b_hp, nullptr);

  // energy (fused o_proj + tanh + v_e reduce)
  gemm128_energy<<<dim3(64, 8), blk, 0, stream>>>(outputs, W_op, b_op, hp, v_e, energy);

  // softmax + ctx + cat3
  softmax_ctx_cat<<<dim3(B_), blk, 0, stream>>>(energy, outputs, hidden, emb, x, cat3);

  // gi = [emb_x|ctx] @ W_ih^T + b_ih   (A = cat3 cols 1000..3619)
  gemm_tn<EP_BIAS><<<dim3(2, 47), blk, 0, stream>>>(
      cat3 + H_, CAT, W_ih, GRUK, gi, 3 * H_, B_, 3 * H_, GRUK, b_ih, nullptr);

  // gh = hidden @ W_hh^T + b_hh
  gemm_tn<EP_BIAS><<<dim3(2, 47), blk, 0, stream>>>(
      hidden, H_, W_hh, H_, gh, 3 * H_, B_, 3 * H_, H_, b_hh, nullptr);

  // h_new
  gru_combine<<<dim3((B_ * H_ + 255) / 256), blk, 0, stream>>>(gi, gh, hidden, hout);

  // mo_in = hidden@W_lh^T + b_lh  (+ emb_x@W_le^T + b_le) (+ ctx@W_wv^T + b_wv), maxpair
  gemm_tn<EP_BIAS><<<dim3(2, 16), blk, 0, stream>>>(
      hidden, H_, W_lh, H_, mo_in, 2 * M_, B_, 2 * M_, H_, b_lh, nullptr);
  gemm_tn<EP_ACCBIAS><<<dim3(2, 16), blk, 0, stream>>>(
      cat3 + H_, CAT, W_le, E_, mo_in, 2 * M_, B_, 2 * M_, E_, b_le, nullptr);
  gemm_tn<EP_ACC_MAXPAIR><<<dim3(2, 16), blk, 0, stream>>>(
      cat3 + H_ + E_, CAT, W_wv, 2 * H_, mo, M_, B_, 2 * M_, 2 * H_, b_wv, mo_in);

  // prediction = mo @ W_pred^T + b_pred
  gemm_tn<EP_BIAS><<<dim3(2, 469), blk, 0, stream>>>(
      mo, M_, W_pred, M_, pred, V_, B_, V_, M_, b_pred, nullptr);
}

// Round 2
// 236.505 us; speedup vs baseline: 4.6869x; 4.6869x over previous
//
#include <hip/hip_runtime.h>
#include <hip/hip_bf16.h>
#include <math.h>

typedef short bf16x8 __attribute__((ext_vector_type(8)));
typedef float f32x4 __attribute__((ext_vector_type(4)));

namespace {
constexpr int B_ = 128;
constexpr int S_ = 64;
constexpr int H_ = 1000;
constexpr int A_ = 1000;
constexpr int M_ = 500;
constexpr int V_ = 30000;
constexpr int E_ = 620;

// padded dims
constexpr int KP_OUT  = 2048;  // K=2000 (o_proj / ctx width)
constexpr int KP_HP   = 1024;  // K=1000
constexpr int KP_IH   = 2688;  // K=2620
constexpr int KP_MO   = 3648;  // K=3620
constexpr int KP_PRED = 512;   // K=500
constexpr int LD_CAT  = 3712;  // [hidden 1000 | emb 620 | ctx 2000 | pad]
constexpr int NP_A    = 1024;  // A_/2M padded rows
constexpr int NP_3H   = 3072;
constexpr int NP_PRED = 30080;

__device__ __forceinline__ unsigned short f2b(float f) {
  __hip_bfloat16 h = __float2bfloat16(f);
  return *reinterpret_cast<unsigned short*>(&h);
}
__device__ __forceinline__ float sigmoidf_(float x) {
  return 1.0f / (1.0f + __expf(-x));
}

__device__ __forceinline__ void load_lds16(const void* g, void* l) {
  auto gp = reinterpret_cast<const __attribute__((address_space(1))) char*>(
      reinterpret_cast<uintptr_t>(g));
  unsigned loff = (unsigned)(uintptr_t)l;
  auto lp = reinterpret_cast<__attribute__((address_space(3))) char*>(loff);
  __builtin_amdgcn_global_load_lds(gp, lp, 16, 0, 0);
}
}  // namespace

// ---------------------------------------------------------------------------
// cast f32 (R,K) -> bf16 (Rp,Kp) zero-padded. 8 elems/thread, grid-stride.
// ---------------------------------------------------------------------------
__global__ __launch_bounds__(256) void cast_pad(
    const float* __restrict__ src, int R, int K,
    unsigned short* __restrict__ dst, int Rp, int Kp)
{
  typedef unsigned short us8 __attribute__((ext_vector_type(8)));
  const long total = (long)Rp * (Kp >> 3);
  for (long i = (long)blockIdx.x * 256 + threadIdx.x; i < total;
       i += (long)gridDim.x * 256) {
    const int r = (int)(i / (Kp >> 3));
    const int c0 = (int)(i % (Kp >> 3)) * 8;
    us8 o;
    if (r < R && c0 + 8 <= K) {
      const float4 f0 = *(const float4*)(src + (size_t)r * K + c0);
      const float4 f1 = *(const float4*)(src + (size_t)r * K + c0 + 4);
      o[0] = f2b(f0.x); o[1] = f2b(f0.y); o[2] = f2b(f0.z); o[3] = f2b(f0.w);
      o[4] = f2b(f1.x); o[5] = f2b(f1.y); o[6] = f2b(f1.z); o[7] = f2b(f1.w);
    } else {
#pragma unroll
      for (int j = 0; j < 8; ++j) {
        float v = (r < R && c0 + j < K) ? src[(size_t)r * K + c0 + j] : 0.f;
        o[j] = f2b(v);
      }
    }
    *(us8*)(dst + (size_t)r * Kp + c0) = o;
  }
}

// cast f32 (R,K) -> bf16 slice of dst at column offset coff (ld = ldd). 4/thr.
__global__ __launch_bounds__(256) void cast_slice(
    const float* __restrict__ src, int R, int K,
    unsigned short* __restrict__ dst, int ldd, int coff)
{
  typedef unsigned short us4 __attribute__((ext_vector_type(4)));
  const long total = (long)R * (K >> 2);
  for (long i = (long)blockIdx.x * 256 + threadIdx.x; i < total;
       i += (long)gridDim.x * 256) {
    const int r = (int)(i / (K >> 2));
    const int c0 = (int)(i % (K >> 2)) * 4;
    const float4 f = *(const float4*)(src + (size_t)r * K + c0);
    us4 o;
    o[0] = f2b(f.x); o[1] = f2b(f.y); o[2] = f2b(f.z); o[3] = f2b(f.w);
    *(us4*)(dst + (size_t)r * ldd + coff + c0) = o;
  }
}

// ---------------------------------------------------------------------------
// bf16 MFMA GEMM: C[M,N] = A[M,K] @ B[N,K]^T.  128x128 tile, BK=64, 4 waves.
// st_16x32 XOR swizzle applied via pre-swizzled global source (linear LDS
// dest for global_load_lds) + swizzled ds_read.
// EP_ATOMIC: atomicAdd into padded C (split-K over grid.z).
// EP_STORE : C = acc + bias[c], guard c < N.
// EP_ENERGY: energy[r] += sum_c tanh(acc + bias[c]+bias2[c]+hp[b,c]) * ve[c]
// ---------------------------------------------------------------------------
enum { EP_ATOMIC = 0, EP_STORE = 1, EP_ENERGY = 2 };

template <int EPI>
__global__ __launch_bounds__(256, 2) void gemm_bf16(
    const unsigned short* __restrict__ Abf, int ldA,
    const unsigned short* __restrict__ Bbf, int ldB,
    float* __restrict__ Cout, int ldc, int N, int nK,
    const float* __restrict__ bias,
    const float* __restrict__ bias2, const float* __restrict__ hp,
    const float* __restrict__ ve, float* __restrict__ energy)
{
  __shared__ __align__(16) char lds[33792];
  char* As = lds;
  char* Bs = lds + 16384;
  float* red = (float*)(lds + 32768);

  const int t = threadIdx.x;
  const int lane = t & 63, wid = t >> 6;
  const int wm = wid >> 1, wn = wid & 1;
  const int l15 = lane & 15, l4 = lane >> 4;
  const int m0 = blockIdx.x * 128, n0 = blockIdx.y * 128;
  const int z = blockIdx.z, Z = gridDim.z;
  const int ks = (int)((long)nK * z / Z), ke = (int)((long)nK * (z + 1) / Z);

  f32x4 acc[4][4] = {};

  for (int kst = ks; kst < ke; ++kst) {
    const int k0 = kst * 64;
#pragma unroll
    for (int c = 0; c < 4; ++c) {
      const unsigned ou = c * 4096 + wid * 1024;
      const unsigned oo = ou + lane * 16;
      const unsigned row = oo >> 7, cb = oo & 127u;
      const unsigned scb = cb ^ ((row & 7u) << 4);
      const char* g = (const char*)Abf + ((size_t)(m0 + row) * ldA + k0) * 2 + scb;
      load_lds16(g, As + ou);
    }
#pragma unroll
    for (int c = 0; c < 4; ++c) {
      const unsigned ou = c * 4096 + wid * 1024;
      const unsigned oo = ou + lane * 16;
      const unsigned row = oo >> 7, cb = oo & 127u;
      const unsigned scb = cb ^ ((row & 7u) << 4);
      const char* g = (const char*)Bbf + ((size_t)(n0 + row) * ldB + k0) * 2 + scb;
      load_lds16(g, Bs + ou);
    }
    __syncthreads();  // drains vmcnt -> LDS tiles ready

#pragma unroll
    for (int kk = 0; kk < 2; ++kk) {
      bf16x8 af[4], bfr[4];
#pragma unroll
      for (int i = 0; i < 4; ++i) {
        const unsigned ra = wm * 64 + i * 16 + l15;
        const unsigned ca = (unsigned)(kk * 64 + l4 * 16) ^ ((ra & 7u) << 4);
        af[i] = *(const bf16x8*)(As + ra * 128 + ca);
        const unsigned rb = wn * 64 + i * 16 + l15;
        const unsigned cb2 = (unsigned)(kk * 64 + l4 * 16) ^ ((rb & 7u) << 4);
        bfr[i] = *(const bf16x8*)(Bs + rb * 128 + cb2);
      }
#pragma unroll
      for (int i = 0; i < 4; ++i)
#pragma unroll
        for (int j = 0; j < 4; ++j)
          acc[i][j] = __builtin_amdgcn_mfma_f32_16x16x32_bf16(af[i], bfr[j],
                                                              acc[i][j], 0, 0, 0);
    }
    __syncthreads();  // all reads done before next-tile overwrite
  }

  if constexpr (EPI == EP_ENERGY) {
    const int bb = (m0 >> 6) + wm;  // batch index, wave-uniform
    float bsum[4], vev[4];
#pragma unroll
    for (int j = 0; j < 4; ++j) {
      const int c = n0 + wn * 64 + j * 16 + l15;
      const bool v = (c < A_);
      bsum[j] = v ? (bias[c] + bias2[c] + hp[(size_t)bb * NP_A + c]) : 0.f;
      vev[j] = v ? ve[c] : 0.f;
    }
#pragma unroll
    for (int i = 0; i < 4; ++i) {
#pragma unroll
      for (int q = 0; q < 4; ++q) {
        float s = 0.f;
#pragma unroll
        for (int j = 0; j < 4; ++j)
          s += tanhf(acc[i][j][q] + bsum[j]) * vev[j];
        s += __shfl_xor(s, 1); s += __shfl_xor(s, 2);
        s += __shfl_xor(s, 4); s += __shfl_xor(s, 8);
        if (l15 == 0) {
          const int rloc = wm * 64 + i * 16 + l4 * 4 + q;
          red[rloc * 2 + wn] = s;
        }
      }
    }
    __syncthreads();
    if (t < 128) atomicAdd(&energy[m0 + t], red[t * 2] + red[t * 2 + 1]);
  } else if constexpr (EPI == EP_ATOMIC) {
#pragma unroll
    for (int i = 0; i < 4; ++i) {
      const int r = m0 + wm * 64 + i * 16 + l4 * 4;
#pragma unroll
      for (int j = 0; j < 4; ++j) {
        const int c = n0 + wn * 64 + j * 16 + l15;
#pragma unroll
        for (int q = 0; q < 4; ++q)
          atomicAdd(&Cout[(size_t)(r + q) * ldc + c], acc[i][j][q]);
      }
    }
  } else {  // EP_STORE
#pragma unroll
    for (int i = 0; i < 4; ++i) {
      const int r = m0 + wm * 64 + i * 16 + l4 * 4;
#pragma unroll
      for (int j = 0; j < 4; ++j) {
        const int c = n0 + wn * 64 + j * 16 + l15;
        if (c < N) {
#pragma unroll
          for (int q = 0; q < 4; ++q)
            Cout[(size_t)(r + q) * ldc + c] = acc[i][j][q] + bias[c];
        }
      }
    }
  }
}

// ---------------------------------------------------------------------------
// Per-b: wave-parallel softmax over S=64, ctx = attn @ outputs,
// build cat3 (bf16, ld 3712) = [hidden | emb_x | ctx | zero-pad]
// ---------------------------------------------------------------------------
__global__ __launch_bounds__(256) void softmax_ctx_cat(
    const float* __restrict__ energy, const float* __restrict__ outputs,
    const float* __restrict__ hidden, const float* __restrict__ emb,
    const int* __restrict__ x, unsigned short* __restrict__ cat3)
{
  typedef unsigned short us4 __attribute__((ext_vector_type(4)));
  const int b = blockIdx.x;
  const int t = threadIdx.x;
  __shared__ float attn[S_];
  __shared__ float sinv_s;

  if (t < 64) {
    const float e = energy[b * S_ + t];
    float m = e;
#pragma unroll
    for (int w = 1; w < 64; w <<= 1) m = fmaxf(m, __shfl_xor(m, w));
    const float p = __expf(e - m);
    float s = p;
#pragma unroll
    for (int w = 1; w < 64; w <<= 1) s += __shfl_xor(s, w);
    attn[t] = p;
    if (t == 0) sinv_s = 1.f / s;
  }
  __syncthreads();
  const float inv = sinv_s;
  unsigned short* catb = cat3 + (size_t)b * LD_CAT;

  // ctx -> cols 1620..3619
  const float4* out4 = (const float4*)(outputs + (size_t)b * S_ * 2 * H_);
  for (int kk = t; kk < (2 * H_) / 4; kk += 256) {
    float4 a = make_float4(0.f, 0.f, 0.f, 0.f);
    for (int s = 0; s < S_; ++s) {
      const float w = attn[s];
      const float4 o = out4[(size_t)s * (2 * H_ / 4) + kk];
      a.x = fmaf(w, o.x, a.x); a.y = fmaf(w, o.y, a.y);
      a.z = fmaf(w, o.z, a.z); a.w = fmaf(w, o.w, a.w);
    }
    us4 v;
    v[0] = f2b(a.x * inv); v[1] = f2b(a.y * inv);
    v[2] = f2b(a.z * inv); v[3] = f2b(a.w * inv);
    *(us4*)(catb + 1620 + kk * 4) = v;
  }
  // hidden -> cols 0..999
  for (int kk = t; kk < H_ / 4; kk += 256) {
    const float4 f = *(const float4*)(hidden + (size_t)b * H_ + kk * 4);
    us4 v; v[0] = f2b(f.x); v[1] = f2b(f.y); v[2] = f2b(f.z); v[3] = f2b(f.w);
    *(us4*)(catb + kk * 4) = v;
  }
  // emb_x -> cols 1000..1619
  const int xi = x[b];
  for (int kk = t; kk < E_ / 4; kk += 256) {
    const float4 f = *(const float4*)(emb + (size_t)xi * E_ + kk * 4);
    us4 v; v[0] = f2b(f.x); v[1] = f2b(f.y); v[2] = f2b(f.z); v[3] = f2b(f.w);
    *(us4*)(catb + 1000 + kk * 4) = v;
  }
  // zero pad cols 3620..3711
  for (int kk = t; kk < (LD_CAT - 3620) / 4; kk += 256) {
    us4 v; v[0] = 0; v[1] = 0; v[2] = 0; v[3] = 0;
    *(us4*)(catb + 3620 + kk * 4) = v;
  }
}

// ---------------------------------------------------------------------------
// GRU combine (adds b_ih/b_hh here; gi/gh are bias-free accumulations)
// ---------------------------------------------------------------------------
__global__ __launch_bounds__(256) void gru_combine(
    const float* __restrict__ gi, const float* __restrict__ gh,
    const float* __restrict__ b_ih, const float* __restrict__ b_hh,
    const float* __restrict__ hidden, float* __restrict__ hout)
{
  const int idx = blockIdx.x * 256 + threadIdx.x;
  if (idx >= B_ * H_) return;
  const int b = idx / H_, h = idx - b * H_;
  const float* gib = gi + (size_t)b * NP_3H;
  const float* ghb = gh + (size_t)b * NP_3H;
  const float ir = gib[h] + b_ih[h];
  const float iz = gib[H_ + h] + b_ih[H_ + h];
  const float in = gib[2 * H_ + h] + b_ih[2 * H_ + h];
  const float hr = ghb[h] + b_hh[h];
  const float hz = ghb[H_ + h] + b_hh[H_ + h];
  const float hn = ghb[2 * H_ + h] + b_hh[2 * H_ + h];
  const float r = sigmoidf_(ir + hr);
  const float zz = sigmoidf_(iz + hz);
  const float n = tanhf(in + r * hn);
  hout[idx] = (1.f - zz) * n + zz * hidden[idx];
}

// ---------------------------------------------------------------------------
// maxout pairs + bias + cast to bf16 (128 x 512, zero-padded)
// ---------------------------------------------------------------------------
__global__ __launch_bounds__(256) void maxpair_cast(
    const float* __restrict__ mo_in,  // ld 1024
    const float* __restrict__ b_lh, const float* __restrict__ b_le,
    const float* __restrict__ b_wv, unsigned short* __restrict__ mo_bf)
{
  const int idx = blockIdx.x * 256 + threadIdx.x;
  if (idx >= B_ * KP_PRED) return;
  const int r = idx >> 9, c = idx & 511;
  unsigned short o = 0;
  if (c < M_) {
    const int j0 = 2 * c, j1 = 2 * c + 1;
    const float v0 = mo_in[(size_t)r * NP_A + j0] + b_lh[j0] + b_le[j0] + b_wv[j0];
    const float v1 = mo_in[(size_t)r * NP_A + j1] + b_lh[j1] + b_le[j1] + b_wv[j1];
    o = f2b(fmaxf(v0, v1));
  }
  mo_bf[idx] = o;
}

// ---------------------------------------------------------------------------
extern "C" void kernel_launch(void* const* d_in, const int* in_sizes, int n_in,
                              void* d_out, int out_size, void* d_ws, size_t ws_size,
                              hipStream_t stream)
{
  const int*   x       = (const int*)  d_in[0];
  const float* hidden  = (const float*)d_in[1];
  const float* outputs = (const float*)d_in[2];
  const float* emb     = (const float*)d_in[3];
  const float* W_hp    = (const float*)d_in[4];
  const float* b_hp    = (const float*)d_in[5];
  const float* W_op    = (const float*)d_in[6];
  const float* b_op    = (const float*)d_in[7];
  const float* v_e     = (const float*)d_in[8];
  const float* W_ih    = (const float*)d_in[9];
  const float* W_hh    = (const float*)d_in[10];
  const float* b_ih    = (const float*)d_in[11];
  const float* b_hh    = (const float*)d_in[12];
  const float* W_wv    = (const float*)d_in[13];
  const float* b_wv    = (const float*)d_in[14];
  const float* W_lh    = (const float*)d_in[15];
  const float* b_lh    = (const float*)d_in[16];
  const float* W_le    = (const float*)d_in[17];
  const float* b_le    = (const float*)d_in[18];
  const float* W_pred  = (const float*)d_in[19];
  const float* b_pred  = (const float*)d_in[20];

  char* w = (char*)d_ws;
  auto alloc = [&](size_t bytes) {
    char* p = w; w += (bytes + 255) & ~(size_t)255; return p;
  };
  unsigned short* outputs_bf = (unsigned short*)alloc((size_t)8192 * KP_OUT * 2);
  unsigned short* W_op_bf    = (unsigned short*)alloc((size_t)NP_A * KP_OUT * 2);
  unsigned short* W_hp_bf    = (unsigned short*)alloc((size_t)NP_A * KP_HP * 2);
  unsigned short* W_ih_bf    = (unsigned short*)alloc((size_t)NP_3H * KP_IH * 2);
  unsigned short* W_hh_bf    = (unsigned short*)alloc((size_t)NP_3H * KP_HP * 2);
  unsigned short* Wmo_bf     = (unsigned short*)alloc((size_t)NP_A * KP_MO * 2);
  unsigned short* W_pred_bf  = (unsigned short*)alloc((size_t)NP_PRED * KP_PRED * 2);
  unsigned short* hidden_bf  = (unsigned short*)alloc((size_t)B_ * KP_HP * 2);
  unsigned short* cat3_bf    = (unsigned short*)alloc((size_t)B_ * LD_CAT * 2);
  unsigned short* mo_bf      = (unsigned short*)alloc((size_t)B_ * KP_PRED * 2);
  float* hp     = (float*)alloc((size_t)B_ * NP_A * 4);
  float* energy = (float*)alloc((size_t)B_ * S_ * 4);
  float* gi     = (float*)alloc((size_t)B_ * NP_3H * 4);
  float* gh     = (float*)alloc((size_t)B_ * NP_3H * 4);
  float* mo_in  = (float*)alloc((size_t)B_ * NP_A * 4);

  float* pred = (float*)d_out;
  float* hout = pred + (size_t)B_ * V_;

  // zero atomic accumulators
  hipMemsetAsync(hp, 0, (size_t)B_ * NP_A * 4, stream);
  hipMemsetAsync(energy, 0, (size_t)B_ * S_ * 4, stream);
  hipMemsetAsync(gi, 0, (size_t)B_ * NP_3H * 4, stream);
  hipMemsetAsync(gh, 0, (size_t)B_ * NP_3H * 4, stream);
  hipMemsetAsync(mo_in, 0, (size_t)B_ * NP_A * 4, stream);

  const dim3 blk(256);
  auto cg = [](long groups) {
    long b = (groups + 255) / 256; return (unsigned)(b > 8192 ? 8192 : b);
  };

  // casts
  cast_pad<<<cg((long)8192 * KP_OUT / 8), blk, 0, stream>>>(outputs, 8192, 2000, outputs_bf, 8192, KP_OUT);
  cast_pad<<<cg((long)NP_A * KP_OUT / 8), blk, 0, stream>>>(W_op, A_, 2000, W_op_bf, NP_A, KP_OUT);
  cast_pad<<<cg((long)NP_A * KP_HP / 8), blk, 0, stream>>>(W_hp, A_, H_, W_hp_bf, NP_A, KP_HP);
  cast_pad<<<cg((long)NP_3H * KP_IH / 8), blk, 0, stream>>>(W_ih, 3 * H_, 2620, W_ih_bf, NP_3H, KP_IH);
  cast_pad<<<cg((long)NP_3H * KP_HP / 8), blk, 0, stream>>>(W_hh, 3 * H_, H_, W_hh_bf, NP_3H, KP_HP);
  cast_pad<<<cg((long)NP_PRED * KP_PRED / 8), blk, 0, stream>>>(W_pred, V_, M_, W_pred_bf, NP_PRED, KP_PRED);
  cast_pad<<<cg((long)B_ * KP_HP / 8), blk, 0, stream>>>(hidden, B_, H_, hidden_bf, B_, KP_HP);
  cast_slice<<<cg((long)A_ * H_ / 4), blk, 0, stream>>>(W_lh, A_, H_, Wmo_bf, KP_MO, 0);
  cast_slice<<<cg((long)A_ * E_ / 4), blk, 0, stream>>>(W_le, A_, E_, Wmo_bf, KP_MO, 1000);
  cast_slice<<<cg((long)A_ * 2 * H_ / 4), blk, 0, stream>>>(W_wv, A_, 2 * H_, Wmo_bf, KP_MO, 1620);

  // h_proj (atomic into hp, split-K 4)
  gemm_bf16<EP_ATOMIC><<<dim3(1, 8, 4), blk, 0, stream>>>(
      hidden_bf, KP_HP, W_hp_bf, KP_HP, hp, NP_A, A_, KP_HP / 64,
      nullptr, nullptr, nullptr, nullptr, nullptr);

  // energy (fused o_proj + tanh + v_e reduce)
  gemm_bf16<EP_ENERGY><<<dim3(64, 8, 1), blk, 0, stream>>>(
      outputs_bf, KP_OUT, W_op_bf, KP_OUT, nullptr, 0, A_, KP_OUT / 64,
      b_op, b_hp, hp, v_e, energy);

  // softmax + ctx + cat3 (bf16)
  softmax_ctx_cat<<<dim3(B_), blk, 0, stream>>>(energy, outputs, hidden, emb, x, cat3_bf);

  // gi = [emb_x|ctx] @ W_ih^T  (A = cat3 cols 1000.., zero-padded K)
  gemm_bf16<EP_ATOMIC><<<dim3(1, 24, 4), blk, 0, stream>>>(
      cat3_bf + 1000, LD_CAT, W_ih_bf, KP_IH, gi, NP_3H, 3 * H_, KP_IH / 64,
      nullptr, nullptr, nullptr, nullptr, nullptr);

  // gh = hidden @ W_hh^T  (A = cat3 cols 0.. ; W_hh K-pad is zero)
  gemm_bf16<EP_ATOMIC><<<dim3(1, 24, 2), blk, 0, stream>>>(
      cat3_bf, LD_CAT, W_hh_bf, KP_HP, gh, NP_3H, 3 * H_, KP_HP / 64,
      nullptr, nullptr, nullptr, nullptr, nullptr);

  // mo_in = cat3 @ [W_lh|W_le|W_wv]^T
  gemm_bf16<EP_ATOMIC><<<dim3(1, 8, 8), blk, 0, stream>>>(
      cat3_bf, LD_CAT, Wmo_bf, KP_MO, mo_in, NP_A, 2 * M_, KP_MO / 64,
      nullptr, nullptr, nullptr, nullptr, nullptr);

  // h_new
  gru_combine<<<dim3((B_ * H_ + 255) / 256), blk, 0, stream>>>(
      gi, gh, b_ih, b_hh, hidden, hout);

  // mo (maxout + biases) -> bf16
  maxpair_cast<<<dim3((B_ * KP_PRED + 255) / 256), blk, 0, stream>>>(
      mo_in, b_lh, b_le, b_wv, mo_bf);

  // prediction = mo @ W_pred^T + b_pred
  gemm_bf16<EP_STORE><<<dim3(1, 235, 1), blk, 0, stream>>>(
      mo_bf, KP_PRED, W_pred_bf, KP_PRED, pred, V_, V_, KP_PRED / 64,
      b_pred, nullptr, nullptr, nullptr, nullptr);
}